// Round 13
// baseline (180.253 us; speedup 1.0000x reference)
//
#include <hip/hip_runtime.h>
#include <hip/hip_bf16.h>
#include <stdint.h>

#define NB 4
#define NN 512
#define NH 64

typedef __attribute__((ext_vector_type(4))) float f32x4;
typedef __attribute__((ext_vector_type(2))) float f32x2;
typedef __attribute__((ext_vector_type(8))) short short8;

__device__ __forceinline__ unsigned short bf16b(float f){
  union { float f; uint32_t u; } c; c.f = f;
  uint32_t u = c.u;
  u += 0x7fffu + ((u >> 16) & 1u);   // round-to-nearest-even
  return (unsigned short)(u >> 16);
}
// single-instruction packed f32->bf16 convert (T12 recipe; no builtin on gfx950).
// Inputs are plain VALU-produced floats (never raw MFMA dests) — proven safe r7.
__device__ __forceinline__ uint32_t pk2(float lo, float hi){
  uint32_t d;
  asm("v_cvt_pk_bf16_f32 %0, %1, %2" : "=v"(d) : "v"(lo), "v"(hi));
  return d;
}
__device__ __forceinline__ float silu(float x){
  float e = __expf(-x);
  return x * __builtin_amdgcn_rcpf(1.0f + e);
}

// ---- software reciprocal: magic seed + 2 Newton steps, pure VALU ----
// Moves the 1/(1+e) off the saturated trans pipe (v_rcp = trans) onto the
// VALU (packable v_pk_fma). rel err ~1e-4 << bf16 rounding (2e-3).
__device__ __forceinline__ f32x2 fast_rcp2(f32x2 d){
  union { float f; uint32_t u; } c0, c1;
  c0.f = d.x; c1.f = d.y;
  c0.u = 0x7EF311C3u - c0.u;
  c1.u = 0x7EF311C3u - c1.u;
  f32x2 r = { c0.f, c1.f };
  r = r * (2.0f - d * r);   // NR1: v_pk_fma (neg mod) + v_pk_mul
  r = r * (2.0f - d * r);   // NR2
  return r;
}
// packed silu: exp stays trans (irreducible); rcp replaced by fast_rcp2.
// exp arg clamped to <=80 so den stays finite (magic trick mishandles inf;
// den ~ 1e34 correctly gives sigma -> 0).
__device__ __forceinline__ f32x2 silu2(f32x2 x){
  float n0 = fminf(-x.x, 80.f);
  float n1 = fminf(-x.y, 80.f);
  f32x2 e = { __expf(n0), __expf(n1) };
  f32x2 den = e + 1.0f;
  return x * fast_rcp2(den);
}

// ---------------- kernel 1: per-node a = h@ew1[0:64] + sp*ew1[129] + eb1,
//                             c = h@ew1[64:128] + sp*ew1[130]
//                  blocks >= 512 pack ew2/fw1 into MFMA A-fragment order ----------------
__launch_bounds__(256)
__global__ void k_precompute(const float* __restrict__ h,
                             const float* __restrict__ vel,
                             const float* __restrict__ ew1,
                             const float* __restrict__ eb1,
                             const float* __restrict__ ew2,
                             const float* __restrict__ fw1,
                             float* __restrict__ wa, float* __restrict__ wc,
                             unsigned short* __restrict__ wef,
                             unsigned short* __restrict__ wff){
  const int tid = threadIdx.x;
  if (blockIdx.x >= 512){
    // weight fragment pack: frag element f = ((kk*4+mt)*64 + lane)*8 + e
    // k-dim: krow = kk*32 + (lane>>4)*8 + e
    // ew2 out-channel is PERMUTED so GEMM1's D-layout IS GEMM2's B-fragment:
    //   channel(mt, dr) = 32*(mt>>1) + 8*(dr>>2) + 4*(mt&1) + (dr&3), dr=lane&15
    // fw1's k-dim then receives m-channels in natural order -> unpermuted pack.
    const int idx = (blockIdx.x - 512) * 256 + tid;   // 0..8191
    const int mat = idx >> 12;
    const int r = idx & 4095;
    const int e2 = r & 7;
    const int lane = (r >> 3) & 63;
    const int mtkk = r >> 9;
    const int kk = mtkk >> 2, mt = mtkk & 3;
    const int krow = kk*32 + (lane >> 4)*8 + e2;
    const int dr = lane & 15;
    const int col_nat  = mt*16 + dr;                                   // fw1
    const int col_perm = 32*(mt>>1) + 8*(dr>>2) + 4*(mt&1) + (dr&3);   // ew2
    if (mat) wff[r] = bf16b(fw1[krow*NH + col_nat]);
    else     wef[r] = bf16b(ew2[krow*NH + col_perm]);
    return;
  }
  const int row = blockIdx.x * 4 + (tid >> 6);   // b*N + n
  const int t = tid & 63;
  const float* hr = h + row * NH;
  const float vx = vel[row*2], vy = vel[row*2+1];
  const float sp = vx*vx + vy*vy;
  float aa = eb1[t] + sp * ew1[129*NH + t];
  float cc =          sp * ew1[130*NH + t];
  #pragma unroll 8
  for (int k = 0; k < NH; ++k){
    float hk = hr[k];
    aa += hk * ew1[k*NH + t];
    cc += hk * ew1[(NH + k)*NH + t];
  }
  wa[row*NH + t] = aa;
  wc[row*NH + t] = cc;
}

// ---------------- kernel 2: per (b,i) block, all 512 edges, MFMA edge MLPs ----------------
// NOTE: NEVER set __launch_bounds__ min-waves on this kernel (r2: VGPR 64 +
// 765MB spill; r10: VGPR 84 + 412MB spill). No hand-written VOP3P f32 asm (r5).
// Weight fragments live in LDS (16KB; r11: VGPR 124->64, no spill).
// unroll 2 (r12). r13: rcp -> magic+2NR (trans-pipe relief; issue-bound model).
__launch_bounds__(256)
__global__ void k_edges(const float* __restrict__ pos,
                        const float* __restrict__ vel,
                        const float* __restrict__ wa,
                        const float* __restrict__ wc,
                        const float* __restrict__ ew1,
                        const float* __restrict__ eb2,
                        const float* __restrict__ fb1,
                        const float* __restrict__ fw2,
                        const float* __restrict__ fb2,
                        const unsigned short* __restrict__ wef,
                        const unsigned short* __restrict__ wff,
                        float* __restrict__ wmagg,
                        float* __restrict__ outF){
  const int row = blockIdx.x;       // b*N + i
  const int b = row >> 9;
  const int i = row & (NN - 1);
  const int tid = threadIdx.x;
  const int l = tid & 63;
  const int w = tid >> 6;
  const int e = l & 15;             // this lane's edge within the 16-edge tile
  const int g = l >> 4;             // lane group (k-slice)
  const int bN = b * NN;

  // weight MFMA fragments in LDS: swef/swff[fi*64 + lane], fi = kk*4+mt.
  // 2 x 8KB; read per-MFMA as ds_read_b128 (consecutive lanes -> consecutive
  // 16B, standard fast path). Frees ~64 persistent VGPRs vs round-9.
  __shared__ short8 swef[512];
  __shared__ short8 swff[512];
  // loop-invariant bias/weight vectors -> LDS (broadcast + conflict-free)
  __shared__ alignas(16) float seb2[64];
  __shared__ alignas(16) float sfb1[64];
  __shared__ alignas(16) float sfw2[64];
  {
    const short8* gwef = (const short8*)wef;
    const short8* gwff = (const short8*)wff;
    #pragma unroll
    for (int q = 0; q < 2; ++q){
      swef[q*256 + tid] = gwef[q*256 + tid];
      swff[q*256 + tid] = gwff[q*256 + tid];
    }
    if (tid < 64){
      seb2[tid] = eb2[tid];
      sfb1[tid] = fb1[tid];
      sfw2[tid] = fw2[tid];
    }
  }

  const float pix = pos[row*2], piy = pos[row*2+1];
  const float vix = vel[row*2], viy = vel[row*2+1];
  const float fb2s = fb2[0];

  // per-lane persistent operand slices (k range = 8g..8g+7 and 32+8g..+7)
  const float* arow = wa + row * NH;
  const f32x4 af0a = *(const f32x4*)(arow + 8*g);
  const f32x4 af0b = *(const f32x4*)(arow + 8*g + 4);
  const f32x4 af1a = *(const f32x4*)(arow + 32 + 8*g);
  const f32x4 af1b = *(const f32x4*)(arow + 32 + 8*g + 4);
  const float* wD = ew1 + 128*NH;   // dist_sq row
  const f32x4 d0a = *(const f32x4*)(wD + 8*g);
  const f32x4 d0b = *(const f32x4*)(wD + 8*g + 4);
  const f32x4 d1a = *(const f32x4*)(wD + 32 + 8*g);
  const f32x4 d1b = *(const f32x4*)(wD + 32 + 8*g + 4);
  const float* wP = ew1 + 131*NH;   // approach row
  const f32x4 p0a = *(const f32x4*)(wP + 8*g);
  const f32x4 p0b = *(const f32x4*)(wP + 8*g + 4);
  const f32x4 p1a = *(const f32x4*)(wP + 32 + 8*g);
  const f32x4 p1b = *(const f32x4*)(wP + 32 + 8*g + 4);

  f32x2 magg01[4], magg23[4];
  #pragma unroll
  for (int mt = 0; mt < 4; ++mt){
    magg01[mt] = (f32x2){0.f, 0.f};
    magg23[mt] = (f32x2){0.f, 0.f};
  }
  float fx = 0.f, fy = 0.f;

  __syncthreads();   // LDS staging visible

  #pragma unroll 2
  for (int it = 0; it < 8; ++it){
    const int jbase = (w + 4*it) * 16;
    const int j = jbase + e;
    const float2 pj = *(const float2*)(pos + (bN + j)*2);
    const float2 vj = *(const float2*)(vel + (bN + j)*2);
    const float rx = pj.x - pix, ry = pj.y - piy;
    const float ds = rx*rx + ry*ry;
    const float inv = __builtin_amdgcn_rsqf(ds + 1e-8f);
    const float nx = rx*inv, ny = ry*inv;
    const float ap = (vj.x - vix)*nx + (vj.y - viy)*ny;
    const float maskv = (j != i) ? 1.0f : 0.0f;
    const f32x2 ds2 = {ds, ds};
    const f32x2 ap2 = {ap, ap};
    const f32x2 mask2 = {maskv, maskv};

    const float* crow = wc + (bN + j)*NH;
    const f32x4 c0a = *(const f32x4*)(crow + 8*g);
    const f32x4 c0b = *(const f32x4*)(crow + 8*g + 4);
    const f32x4 c1a = *(const f32x4*)(crow + 32 + 8*g);
    const f32x4 c1b = *(const f32x4*)(crow + 32 + 8*g + 4);

    // x1 = silu(a_i + c_j + ds*wD + ap*wP), built directly in B-fragment layout
    // (vector f32x2 arithmetic -> compiler-selected v_pk_add/v_pk_fma)
    short8 bx[2];
    {
      union { uint32_t u[4]; short8 s; } cv;
      f32x2 s01 = silu2(af0a.xy + c0a.xy + d0a.xy*ds2 + p0a.xy*ap2);
      f32x2 s23 = silu2(af0a.zw + c0a.zw + d0a.zw*ds2 + p0a.zw*ap2);
      cv.u[0] = pk2(s01.x, s01.y); cv.u[1] = pk2(s23.x, s23.y);
      f32x2 s45 = silu2(af0b.xy + c0b.xy + d0b.xy*ds2 + p0b.xy*ap2);
      f32x2 s67 = silu2(af0b.zw + c0b.zw + d0b.zw*ds2 + p0b.zw*ap2);
      cv.u[2] = pk2(s45.x, s45.y); cv.u[3] = pk2(s67.x, s67.y);
      bx[0] = cv.s;
    }
    {
      union { uint32_t u[4]; short8 s; } cv;
      f32x2 s01 = silu2(af1a.xy + c1a.xy + d1a.xy*ds2 + p1a.xy*ap2);
      f32x2 s23 = silu2(af1a.zw + c1a.zw + d1a.zw*ds2 + p1a.zw*ap2);
      cv.u[0] = pk2(s01.x, s01.y); cv.u[1] = pk2(s23.x, s23.y);
      f32x2 s45 = silu2(af1b.xy + c1b.xy + d1b.xy*ds2 + p1b.xy*ap2);
      f32x2 s67 = silu2(af1b.zw + c1b.zw + d1b.zw*ds2 + p1b.zw*ap2);
      cv.u[2] = pk2(s45.x, s45.y); cv.u[3] = pk2(s67.x, s67.y);
      bx[1] = cv.s;
    }

    // GEMM1': m^T = ew2p^T @ x1^T   (D: lane(g,e) holds channel 32*(mt>>1)+8g+4*(mt&1)+r, edge e)
    // A-fragments streamed from LDS (ds_read_b128)
    f32x4 accm[4];
    #pragma unroll
    for (int mt = 0; mt < 4; ++mt){
      accm[mt] = *(const f32x4*)(seb2 + 32*(mt>>1) + 8*g + 4*(mt&1));   // permuted bias C-init (LDS)
      accm[mt] = __builtin_amdgcn_mfma_f32_16x16x32_bf16(swef[(0*4 + mt)*64 + l], bx[0], accm[mt], 0, 0, 0);
      accm[mt] = __builtin_amdgcn_mfma_f32_16x16x32_bf16(swef[(1*4 + mt)*64 + l], bx[1], accm[mt], 0, 0, 0);
    }

    // m = silu(.), accumulate masked m_agg (packed), pack to bf16 pairs
    uint32_t pkm[4][2];
    #pragma unroll
    for (int mt = 0; mt < 4; ++mt){
      f32x2 m01 = silu2(accm[mt].xy);
      f32x2 m23 = silu2(accm[mt].zw);
      magg01[mt] = magg01[mt] + m01 * mask2;
      magg23[mt] = magg23[mt] + m23 * mask2;
      pkm[mt][0] = pk2(m01.x, m01.y);
      pkm[mt][1] = pk2(m23.x, m23.y);
    }

    // channel permutation makes D-layout == GEMM2 B-fragment: no shuffles.
    short8 bm[2];
    #pragma unroll
    for (int kk = 0; kk < 2; ++kk){
      union { uint32_t u[4]; short8 s; } cv;
      cv.u[0] = pkm[2*kk][0];
      cv.u[1] = pkm[2*kk][1];
      cv.u[2] = pkm[2*kk+1][0];
      cv.u[3] = pkm[2*kk+1][1];
      bm[kk] = cv.s;
    }

    // GEMM2': f1^T = fw1^T @ m^T ; then fwt = f1 . fw2 + fb2
    f32x2 pacc = {0.f, 0.f};
    #pragma unroll
    for (int mt = 0; mt < 4; ++mt){
      f32x4 acc2 = *(const f32x4*)(sfb1 + mt*16 + 4*g);
      acc2 = __builtin_amdgcn_mfma_f32_16x16x32_bf16(swff[(0*4 + mt)*64 + l], bm[0], acc2, 0, 0, 0);
      acc2 = __builtin_amdgcn_mfma_f32_16x16x32_bf16(swff[(1*4 + mt)*64 + l], bm[1], acc2, 0, 0, 0);
      const f32x4 f2v = *(const f32x4*)(sfw2 + mt*16 + 4*g);
      pacc = pacc + silu2(acc2.xy) * f2v.xy;
      pacc = pacc + silu2(acc2.zw) * f2v.zw;
    }
    float p = pacc.x + pacc.y;
    p += __shfl_xor(p, 16);
    p += __shfl_xor(p, 32);
    const float fwt = p + fb2s;
    fx += maskv * fwt * nx;
    fy += maskv * fwt * ny;
  }

  // ---- epilogue: reduce m_agg over edge lanes, force over lanes; combine waves via LDS
  __shared__ float smagg[4][64];
  __shared__ float sforce[4][2];

  #pragma unroll
  for (int mt = 0; mt < 4; ++mt){
    #pragma unroll
    for (int r = 0; r < 4; ++r){
      float v = (r < 2) ? ((r & 1) ? magg01[mt].y : magg01[mt].x)
                        : ((r & 1) ? magg23[mt].y : magg23[mt].x);
      v += __shfl_xor(v, 1);
      v += __shfl_xor(v, 2);
      v += __shfl_xor(v, 4);
      v += __shfl_xor(v, 8);
      if (e == 0) smagg[w][32*(mt>>1) + 8*g + 4*(mt&1) + r] = v;   // unpermute
    }
  }
  fx += __shfl_xor(fx, 1); fx += __shfl_xor(fx, 2); fx += __shfl_xor(fx, 4); fx += __shfl_xor(fx, 8);
  fy += __shfl_xor(fy, 1); fy += __shfl_xor(fy, 2); fy += __shfl_xor(fy, 4); fy += __shfl_xor(fy, 8);
  if (l == 0){ sforce[w][0] = fx; sforce[w][1] = fy; }
  __syncthreads();

  if (tid < 64)
    wmagg[row*NH + tid] = smagg[0][tid] + smagg[1][tid] + smagg[2][tid] + smagg[3][tid];
  if (tid == 0){
    outF[row*2]     = sforce[0][0] + sforce[1][0] + sforce[2][0] + sforce[3][0];
    outF[row*2 + 1] = sforce[0][1] + sforce[1][1] + sforce[2][1] + sforce[3][1];
  }
}

// ---------------- kernel 3: node MLP  h_new = silu([h, m_agg]@nw1 + nb1)@nw2 + nb2 ----------------
__launch_bounds__(256)
__global__ void k_node(const float* __restrict__ h,
                       const float* __restrict__ wmagg,
                       const float* __restrict__ nw1,
                       const float* __restrict__ nb1,
                       const float* __restrict__ nw2,
                       const float* __restrict__ nb2,
                       float* __restrict__ outH){
  const int tid = threadIdx.x;
  const int r = tid >> 6;
  const int row = blockIdx.x * 4 + r;
  const int t = tid & 63;
  __shared__ float t1[4][64];
  const float* hr = h + row * NH;
  const float* mr = wmagg + row * NH;
  float acc = nb1[t];
  #pragma unroll 8
  for (int k = 0; k < NH; ++k) acc += hr[k] * nw1[k*NH + t];
  #pragma unroll 8
  for (int k = 0; k < NH; ++k) acc += mr[k] * nw1[(NH + k)*NH + t];
  t1[r][t] = silu(acc);
  __syncthreads();
  float o = nb2[t];
  #pragma unroll 8
  for (int k = 0; k < NH; ++k) o += t1[r][k] * nw2[k*NH + t];
  outH[row*NH + t] = o;
}

extern "C" void kernel_launch(void* const* d_in, const int* in_sizes, int n_in,
                              void* d_out, int out_size, void* d_ws, size_t ws_size,
                              hipStream_t stream){
  const float* h   = (const float*)d_in[0];
  const float* pos = (const float*)d_in[1];
  const float* vel = (const float*)d_in[2];
  const float* ew1 = (const float*)d_in[3];
  const float* eb1 = (const float*)d_in[4];
  const float* ew2 = (const float*)d_in[5];
  const float* eb2 = (const float*)d_in[6];
  const float* fw1 = (const float*)d_in[7];
  const float* fb1 = (const float*)d_in[8];
  const float* fw2 = (const float*)d_in[9];
  const float* fb2 = (const float*)d_in[10];
  const float* nw1 = (const float*)d_in[11];
  const float* nb1 = (const float*)d_in[12];
  const float* nw2 = (const float*)d_in[13];
  const float* nb2 = (const float*)d_in[14];
  float* out = (float*)d_out;

  float* wa    = (float*)d_ws;                 // [B*N*64]
  float* wc    = wa + NB*NN*NH;                // [B*N*64]
  float* wmagg = wc + NB*NN*NH;                // [B*N*64]
  unsigned short* wef = (unsigned short*)(wmagg + NB*NN*NH);  // [4096] bf16
  unsigned short* wff = wef + 4096;                           // [4096] bf16

  k_precompute<<<dim3(544), dim3(256), 0, stream>>>(h, vel, ew1, eb1, ew2, fw1,
                                                    wa, wc, wef, wff);
  k_edges<<<dim3(NB*NN), dim3(256), 0, stream>>>(pos, vel, wa, wc, ew1, eb2, fb1, fw2, fb2,
                                                 wef, wff, wmagg, out + NB*NN*NH);
  k_node<<<dim3(512), dim3(256), 0, stream>>>(h, wmagg, nw1, nb1, nw2, nb2, out);
}

// Round 14
// 157.969 us; speedup vs baseline: 1.1411x; 1.1411x over previous
//
#include <hip/hip_runtime.h>
#include <hip/hip_bf16.h>
#include <stdint.h>

#define NB 4
#define NN 512
#define NH 64
#define LOG2E 1.44269504088896340736f
#define LN2   0.69314718055994530942f

typedef __attribute__((ext_vector_type(4))) float f32x4;
typedef __attribute__((ext_vector_type(2))) float f32x2;
typedef __attribute__((ext_vector_type(8))) short short8;

__device__ __forceinline__ unsigned short bf16b(float f){
  union { float f; uint32_t u; } c; c.f = f;
  uint32_t u = c.u;
  u += 0x7fffu + ((u >> 16) & 1u);   // round-to-nearest-even
  return (unsigned short)(u >> 16);
}
// single-instruction packed f32->bf16 convert (T12 recipe; no builtin on gfx950).
// Inputs are plain VALU-produced floats (never raw MFMA dests) — proven safe r7.
__device__ __forceinline__ uint32_t pk2(float lo, float hi){
  uint32_t d;
  asm("v_cvt_pk_bf16_f32 %0, %1, %2" : "=v"(d) : "v"(lo), "v"(hi));
  return d;
}
__device__ __forceinline__ float silu(float x){
  float e = __expf(-x);
  return x * __builtin_amdgcn_rcpf(1.0f + e);
}

// ---- exp2-domain silu: input t = x*log2e; returns u = t*sigmoid(x) = silu(x)*log2e.
// The log2e/ln2 scales are folded into surrounding affine layers (ln2*log2e = 1),
// so no v_mul-by-log2e issues anywhere in the loop (r13 lesson: VALU ISSUE count
// is the binding resource; v_exp/v_rcp execution overlaps fine).
__device__ __forceinline__ f32x2 silu2t(f32x2 t){
  f32x2 e = { __builtin_amdgcn_exp2f(-t.x), __builtin_amdgcn_exp2f(-t.y) };
  f32x2 den = e + 1.0f;
  f32x2 r = { __builtin_amdgcn_rcpf(den.x), __builtin_amdgcn_rcpf(den.y) };
  return t * r;     // t -> -inf: e=inf, rcp(inf)=0, u=0 — no clamp needed
}

// ---------------- kernel 1: per-node a,c (PRE-SCALED by log2e for exp2 domain);
//                  blocks >= 512 pack ew2/fw1 into MFMA A-fragment order ----------------
__launch_bounds__(256)
__global__ void k_precompute(const float* __restrict__ h,
                             const float* __restrict__ vel,
                             const float* __restrict__ ew1,
                             const float* __restrict__ eb1,
                             const float* __restrict__ ew2,
                             const float* __restrict__ fw1,
                             float* __restrict__ wa, float* __restrict__ wc,
                             unsigned short* __restrict__ wef,
                             unsigned short* __restrict__ wff){
  const int tid = threadIdx.x;
  if (blockIdx.x >= 512){
    // weight fragment pack: frag element f = ((kk*4+mt)*64 + lane)*8 + e
    // k-dim: krow = kk*32 + (lane>>4)*8 + e
    // ew2 out-channel is PERMUTED so GEMM1's D-layout IS GEMM2's B-fragment:
    //   channel(mt, dr) = 32*(mt>>1) + 8*(dr>>2) + 4*(mt&1) + (dr&3), dr=lane&15
    // fw1's k-dim then receives m-channels in natural order -> unpermuted pack.
    const int idx = (blockIdx.x - 512) * 256 + tid;   // 0..8191
    const int mat = idx >> 12;
    const int r = idx & 4095;
    const int e2 = r & 7;
    const int lane = (r >> 3) & 63;
    const int mtkk = r >> 9;
    const int kk = mtkk >> 2, mt = mtkk & 3;
    const int krow = kk*32 + (lane >> 4)*8 + e2;
    const int dr = lane & 15;
    const int col_nat  = mt*16 + dr;                                   // fw1
    const int col_perm = 32*(mt>>1) + 8*(dr>>2) + 4*(mt&1) + (dr&3);   // ew2
    if (mat) wff[r] = bf16b(fw1[krow*NH + col_nat]);
    else     wef[r] = bf16b(ew2[krow*NH + col_perm]);
    return;
  }
  const int row = blockIdx.x * 4 + (tid >> 6);   // b*N + n
  const int t = tid & 63;
  const float* hr = h + row * NH;
  const float vx = vel[row*2], vy = vel[row*2+1];
  const float sp = vx*vx + vy*vy;
  float aa = eb1[t] + sp * ew1[129*NH + t];
  float cc =          sp * ew1[130*NH + t];
  #pragma unroll 8
  for (int k = 0; k < NH; ++k){
    float hk = hr[k];
    aa += hk * ew1[k*NH + t];
    cc += hk * ew1[(NH + k)*NH + t];
  }
  wa[row*NH + t] = aa * LOG2E;   // exp2-domain
  wc[row*NH + t] = cc * LOG2E;
}

// ---------------- kernel 2: per (b,i) block, all 512 edges, MFMA edge MLPs ----------------
// NOTE: NEVER set __launch_bounds__ min-waves on this kernel (r2: VGPR 64 +
// 765MB spill; r10: VGPR 84 + 412MB spill). No hand-written VOP3P f32 asm (r5).
// No fast_rcp NR (r13: +20us — VALU issue-bound, trans overlaps). Weight
// fragments in LDS (r11). unroll 2 (r12). r14: exp2-domain folding — all
// log2e/ln2 scales folded into affine layers; silu = exp2+rcp only.
__launch_bounds__(256)
__global__ void k_edges(const float* __restrict__ pos,
                        const float* __restrict__ vel,
                        const float* __restrict__ wa,
                        const float* __restrict__ wc,
                        const float* __restrict__ ew1,
                        const float* __restrict__ eb2,
                        const float* __restrict__ fb1,
                        const float* __restrict__ fw2,
                        const float* __restrict__ fb2,
                        const unsigned short* __restrict__ wef,
                        const unsigned short* __restrict__ wff,
                        float* __restrict__ wmagg,
                        float* __restrict__ outF){
  const int row = blockIdx.x;       // b*N + i
  const int b = row >> 9;
  const int i = row & (NN - 1);
  const int tid = threadIdx.x;
  const int l = tid & 63;
  const int w = tid >> 6;
  const int e = l & 15;             // this lane's edge within the 16-edge tile
  const int g = l >> 4;             // lane group (k-slice)
  const int bN = b * NN;

  // weight MFMA fragments in LDS: swef/swff[fi*64 + lane], fi = kk*4+mt.
  __shared__ short8 swef[512];
  __shared__ short8 swff[512];
  // loop-invariant bias/weight vectors -> LDS, pre-scaled for exp2 domain:
  //   seb2 = eb2*log2e (C-init -> accm = t2 directly; ew2 unscaled since ln2*log2e=1)
  //   sfb1 = fb1*log2e (C-init -> acc2 = t3 directly; fw1 unscaled)
  //   sfw2 = fw2*ln2   (dot with u3 = silu*log2e gives real force_weight)
  __shared__ alignas(16) float seb2[64];
  __shared__ alignas(16) float sfb1[64];
  __shared__ alignas(16) float sfw2[64];
  {
    const short8* gwef = (const short8*)wef;
    const short8* gwff = (const short8*)wff;
    #pragma unroll
    for (int q = 0; q < 2; ++q){
      swef[q*256 + tid] = gwef[q*256 + tid];
      swff[q*256 + tid] = gwff[q*256 + tid];
    }
    if (tid < 64){
      seb2[tid] = eb2[tid] * LOG2E;
      sfb1[tid] = fb1[tid] * LOG2E;
      sfw2[tid] = fw2[tid] * LN2;
    }
  }

  const float pix = pos[row*2], piy = pos[row*2+1];
  const float vix = vel[row*2], viy = vel[row*2+1];
  const float fb2s = fb2[0];

  // per-lane persistent operand slices; wD/wP scaled by log2e at load (exp2 domain)
  const float* arow = wa + row * NH;
  const f32x4 af0a = *(const f32x4*)(arow + 8*g);
  const f32x4 af0b = *(const f32x4*)(arow + 8*g + 4);
  const f32x4 af1a = *(const f32x4*)(arow + 32 + 8*g);
  const f32x4 af1b = *(const f32x4*)(arow + 32 + 8*g + 4);
  const float* wD = ew1 + 128*NH;   // dist_sq row
  const f32x4 d0a = *(const f32x4*)(wD + 8*g) * LOG2E;
  const f32x4 d0b = *(const f32x4*)(wD + 8*g + 4) * LOG2E;
  const f32x4 d1a = *(const f32x4*)(wD + 32 + 8*g) * LOG2E;
  const f32x4 d1b = *(const f32x4*)(wD + 32 + 8*g + 4) * LOG2E;
  const float* wP = ew1 + 131*NH;   // approach row
  const f32x4 p0a = *(const f32x4*)(wP + 8*g) * LOG2E;
  const f32x4 p0b = *(const f32x4*)(wP + 8*g + 4) * LOG2E;
  const f32x4 p1a = *(const f32x4*)(wP + 32 + 8*g) * LOG2E;
  const f32x4 p1b = *(const f32x4*)(wP + 32 + 8*g + 4) * LOG2E;

  f32x2 magg01[4], magg23[4];
  #pragma unroll
  for (int mt = 0; mt < 4; ++mt){
    magg01[mt] = (f32x2){0.f, 0.f};
    magg23[mt] = (f32x2){0.f, 0.f};
  }
  float fx = 0.f, fy = 0.f;

  __syncthreads();   // LDS staging visible

  #pragma unroll 2
  for (int it = 0; it < 8; ++it){
    const int jbase = (w + 4*it) * 16;
    const int j = jbase + e;
    const float2 pj = *(const float2*)(pos + (bN + j)*2);
    const float2 vj = *(const float2*)(vel + (bN + j)*2);
    const float rx = pj.x - pix, ry = pj.y - piy;
    const float ds = rx*rx + ry*ry;
    const float inv = __builtin_amdgcn_rsqf(ds + 1e-8f);
    const float nx = rx*inv, ny = ry*inv;
    const float ap = (vj.x - vix)*nx + (vj.y - viy)*ny;
    const float maskv = (j != i) ? 1.0f : 0.0f;
    const f32x2 ds2 = {ds, ds};
    const f32x2 ap2 = {ap, ap};
    const f32x2 mask2 = {maskv, maskv};

    const float* crow = wc + (bN + j)*NH;
    const f32x4 c0a = *(const f32x4*)(crow + 8*g);
    const f32x4 c0b = *(const f32x4*)(crow + 8*g + 4);
    const f32x4 c1a = *(const f32x4*)(crow + 32 + 8*g);
    const f32x4 c1b = *(const f32x4*)(crow + 32 + 8*g + 4);

    // t1 = log2e*x1 built directly (all inputs pre-scaled); u1 = silu2t(t1)
    short8 bx[2];
    {
      union { uint32_t u[4]; short8 s; } cv;
      f32x2 s01 = silu2t(af0a.xy + c0a.xy + d0a.xy*ds2 + p0a.xy*ap2);
      f32x2 s23 = silu2t(af0a.zw + c0a.zw + d0a.zw*ds2 + p0a.zw*ap2);
      cv.u[0] = pk2(s01.x, s01.y); cv.u[1] = pk2(s23.x, s23.y);
      f32x2 s45 = silu2t(af0b.xy + c0b.xy + d0b.xy*ds2 + p0b.xy*ap2);
      f32x2 s67 = silu2t(af0b.zw + c0b.zw + d0b.zw*ds2 + p0b.zw*ap2);
      cv.u[2] = pk2(s45.x, s45.y); cv.u[3] = pk2(s67.x, s67.y);
      bx[0] = cv.s;
    }
    {
      union { uint32_t u[4]; short8 s; } cv;
      f32x2 s01 = silu2t(af1a.xy + c1a.xy + d1a.xy*ds2 + p1a.xy*ap2);
      f32x2 s23 = silu2t(af1a.zw + c1a.zw + d1a.zw*ds2 + p1a.zw*ap2);
      cv.u[0] = pk2(s01.x, s01.y); cv.u[1] = pk2(s23.x, s23.y);
      f32x2 s45 = silu2t(af1b.xy + c1b.xy + d1b.xy*ds2 + p1b.xy*ap2);
      f32x2 s67 = silu2t(af1b.zw + c1b.zw + d1b.zw*ds2 + p1b.zw*ap2);
      cv.u[2] = pk2(s45.x, s45.y); cv.u[3] = pk2(s67.x, s67.y);
      bx[1] = cv.s;
    }

    // GEMM1': accm = ew2p^T @ u1 + eb2*log2e = t2 (exp2-domain preact)
    f32x4 accm[4];
    #pragma unroll
    for (int mt = 0; mt < 4; ++mt){
      accm[mt] = *(const f32x4*)(seb2 + 32*(mt>>1) + 8*g + 4*(mt&1));
      accm[mt] = __builtin_amdgcn_mfma_f32_16x16x32_bf16(swef[(0*4 + mt)*64 + l], bx[0], accm[mt], 0, 0, 0);
      accm[mt] = __builtin_amdgcn_mfma_f32_16x16x32_bf16(swef[(1*4 + mt)*64 + l], bx[1], accm[mt], 0, 0, 0);
    }

    // u2 = silu2t(t2) (= m_real*log2e); magg accumulates u2 (x ln2 at epilogue)
    uint32_t pkm[4][2];
    #pragma unroll
    for (int mt = 0; mt < 4; ++mt){
      f32x2 m01 = silu2t(accm[mt].xy);
      f32x2 m23 = silu2t(accm[mt].zw);
      magg01[mt] = magg01[mt] + m01 * mask2;
      magg23[mt] = magg23[mt] + m23 * mask2;
      pkm[mt][0] = pk2(m01.x, m01.y);
      pkm[mt][1] = pk2(m23.x, m23.y);
    }

    // channel permutation makes D-layout == GEMM2 B-fragment: no shuffles.
    short8 bm[2];
    #pragma unroll
    for (int kk = 0; kk < 2; ++kk){
      union { uint32_t u[4]; short8 s; } cv;
      cv.u[0] = pkm[2*kk][0];
      cv.u[1] = pkm[2*kk][1];
      cv.u[2] = pkm[2*kk+1][0];
      cv.u[3] = pkm[2*kk+1][1];
      bm[kk] = cv.s;
    }

    // GEMM2': acc2 = fw1^T @ u2 + fb1*log2e = t3 ; p = sum u3 * (fw2*ln2)
    f32x2 pacc = {0.f, 0.f};
    #pragma unroll
    for (int mt = 0; mt < 4; ++mt){
      f32x4 acc2 = *(const f32x4*)(sfb1 + mt*16 + 4*g);
      acc2 = __builtin_amdgcn_mfma_f32_16x16x32_bf16(swff[(0*4 + mt)*64 + l], bm[0], acc2, 0, 0, 0);
      acc2 = __builtin_amdgcn_mfma_f32_16x16x32_bf16(swff[(1*4 + mt)*64 + l], bm[1], acc2, 0, 0, 0);
      const f32x4 f2v = *(const f32x4*)(sfw2 + mt*16 + 4*g);
      pacc = pacc + silu2t(acc2.xy) * f2v.xy;
      pacc = pacc + silu2t(acc2.zw) * f2v.zw;
    }
    float p = pacc.x + pacc.y;
    p += __shfl_xor(p, 16);
    p += __shfl_xor(p, 32);
    const float fwt = p + fb2s;
    fx += maskv * fwt * nx;
    fy += maskv * fwt * ny;
  }

  // ---- epilogue: reduce m_agg over edge lanes, force over lanes; combine waves via LDS
  __shared__ float smagg[4][64];
  __shared__ float sforce[4][2];

  #pragma unroll
  for (int mt = 0; mt < 4; ++mt){
    #pragma unroll
    for (int r = 0; r < 4; ++r){
      float v = (r < 2) ? ((r & 1) ? magg01[mt].y : magg01[mt].x)
                        : ((r & 1) ? magg23[mt].y : magg23[mt].x);
      v += __shfl_xor(v, 1);
      v += __shfl_xor(v, 2);
      v += __shfl_xor(v, 4);
      v += __shfl_xor(v, 8);
      if (e == 0) smagg[w][32*(mt>>1) + 8*g + 4*(mt&1) + r] = v;   // unpermute
    }
  }
  fx += __shfl_xor(fx, 1); fx += __shfl_xor(fx, 2); fx += __shfl_xor(fx, 4); fx += __shfl_xor(fx, 8);
  fy += __shfl_xor(fy, 1); fy += __shfl_xor(fy, 2); fy += __shfl_xor(fy, 4); fy += __shfl_xor(fy, 8);
  if (l == 0){ sforce[w][0] = fx; sforce[w][1] = fy; }
  __syncthreads();

  if (tid < 64)   // x LN2: magg was accumulated in exp2 domain (u2 = m*log2e)
    wmagg[row*NH + tid] = (smagg[0][tid] + smagg[1][tid] + smagg[2][tid] + smagg[3][tid]) * LN2;
  if (tid == 0){
    outF[row*2]     = sforce[0][0] + sforce[1][0] + sforce[2][0] + sforce[3][0];
    outF[row*2 + 1] = sforce[0][1] + sforce[1][1] + sforce[2][1] + sforce[3][1];
  }
}

// ---------------- kernel 3: node MLP  h_new = silu([h, m_agg]@nw1 + nb1)@nw2 + nb2 ----------------
__launch_bounds__(256)
__global__ void k_node(const float* __restrict__ h,
                       const float* __restrict__ wmagg,
                       const float* __restrict__ nw1,
                       const float* __restrict__ nb1,
                       const float* __restrict__ nw2,
                       const float* __restrict__ nb2,
                       float* __restrict__ outH){
  const int tid = threadIdx.x;
  const int r = tid >> 6;
  const int row = blockIdx.x * 4 + r;
  const int t = tid & 63;
  __shared__ float t1[4][64];
  const float* hr = h + row * NH;
  const float* mr = wmagg + row * NH;
  float acc = nb1[t];
  #pragma unroll 8
  for (int k = 0; k < NH; ++k) acc += hr[k] * nw1[k*NH + t];
  #pragma unroll 8
  for (int k = 0; k < NH; ++k) acc += mr[k] * nw1[(NH + k)*NH + t];
  t1[r][t] = silu(acc);
  __syncthreads();
  float o = nb2[t];
  #pragma unroll 8
  for (int k = 0; k < NH; ++k) o += t1[r][k] * nw2[k*NH + t];
  outH[row*NH + t] = o;
}

extern "C" void kernel_launch(void* const* d_in, const int* in_sizes, int n_in,
                              void* d_out, int out_size, void* d_ws, size_t ws_size,
                              hipStream_t stream){
  const float* h   = (const float*)d_in[0];
  const float* pos = (const float*)d_in[1];
  const float* vel = (const float*)d_in[2];
  const float* ew1 = (const float*)d_in[3];
  const float* eb1 = (const float*)d_in[4];
  const float* ew2 = (const float*)d_in[5];
  const float* eb2 = (const float*)d_in[6];
  const float* fw1 = (const float*)d_in[7];
  const float* fb1 = (const float*)d_in[8];
  const float* fw2 = (const float*)d_in[9];
  const float* fb2 = (const float*)d_in[10];
  const float* nw1 = (const float*)d_in[11];
  const float* nb1 = (const float*)d_in[12];
  const float* nw2 = (const float*)d_in[13];
  const float* nb2 = (const float*)d_in[14];
  float* out = (float*)d_out;

  float* wa    = (float*)d_ws;                 // [B*N*64]
  float* wc    = wa + NB*NN*NH;                // [B*N*64]
  float* wmagg = wc + NB*NN*NH;                // [B*N*64]
  unsigned short* wef = (unsigned short*)(wmagg + NB*NN*NH);  // [4096] bf16
  unsigned short* wff = wef + 4096;                           // [4096] bf16

  k_precompute<<<dim3(544), dim3(256), 0, stream>>>(h, vel, ew1, eb1, ew2, fw1,
                                                    wa, wc, wef, wff);
  k_edges<<<dim3(NB*NN), dim3(256), 0, stream>>>(pos, vel, wa, wc, ew1, eb2, fb1, fw2, fb2,
                                                 wef, wff, wmagg, out + NB*NN*NH);
  k_node<<<dim3(512), dim3(256), 0, stream>>>(h, wmagg, nw1, nb1, nw2, nb2, out);
}